// Round 1
// baseline (304.203 us; speedup 1.0000x reference)
//
#include <hip/hip_runtime.h>
#include <hip/hip_bf16.h>

typedef __attribute__((ext_vector_type(8))) short bf16x8;
typedef __attribute__((ext_vector_type(4))) float f32x4;

#define NH 12
#define HD 64
#define TT 1536
#define CC 768
#define BB 4
#define MM (BB * TT)   // 6144 rows

__device__ __forceinline__ unsigned short f2bf(float f) {
    unsigned int u = __builtin_bit_cast(unsigned int, f);
    return (unsigned short)((u + 0x7FFFu + ((u >> 16) & 1u)) >> 16);  // RNE
}

__global__ __launch_bounds__(256) void convert_k(const float* __restrict__ in,
                                                 unsigned short* __restrict__ out,
                                                 int n4) {
    int i = blockIdx.x * 256 + threadIdx.x;
    if (i >= n4) return;
    float4 v = reinterpret_cast<const float4*>(in)[i];
    ushort4 o = { f2bf(v.x), f2bf(v.y), f2bf(v.z), f2bf(v.w) };
    reinterpret_cast<ushort4*>(out)[i] = o;
}

// ---------------------------------------------------------------------------
// QKV projection GEMM: C[m,n] = sum_k A[m,k] * W[n,k]  (both K-contiguous)
// tile 128x128, 4 waves (each 64x64), BK=32, 16x16x32 bf16 MFMA.
// Epilogue: write bf16 to [B,H,T,D]; z selects q/k/v; q scaled by 0.125.
// ---------------------------------------------------------------------------
__global__ __launch_bounds__(256) void gemm_qkv(
    const unsigned short* __restrict__ xb,
    const unsigned short* __restrict__ wq, const float* __restrict__ bq,
    const unsigned short* __restrict__ wk, const float* __restrict__ bk,
    const unsigned short* __restrict__ wv, const float* __restrict__ bv,
    unsigned short* __restrict__ qo, unsigned short* __restrict__ ko,
    unsigned short* __restrict__ vo) {
    __shared__ unsigned short As[128][40];   // +8 pad: 80B stride -> 2-way max
    __shared__ unsigned short Bs[128][40];

    const int z = blockIdx.z;
    const unsigned short* W = (z == 0) ? wq : (z == 1) ? wk : wv;
    const float* bias = (z == 0) ? bq : (z == 1) ? bk : bv;
    unsigned short* out = (z == 0) ? qo : (z == 1) ? ko : vo;
    const float scale = (z == 0) ? 0.125f : 1.0f;

    const int m0 = blockIdx.y * 128;
    const int n0 = blockIdx.x * 128;
    const int tid = threadIdx.x;
    const int lane = tid & 63;
    const int w = tid >> 6;
    const int wr = w >> 1, wc = w & 1;
    const int fr = lane & 15, fg = lane >> 4;

    f32x4 acc[4][4];
#pragma unroll
    for (int i = 0; i < 4; i++)
#pragma unroll
        for (int j = 0; j < 4; j++) acc[i][j] = (f32x4){0.f, 0.f, 0.f, 0.f};

    for (int k0 = 0; k0 < CC; k0 += 32) {
        __syncthreads();
        for (int c = tid; c < 512; c += 256) {     // 128 rows x 4 colgroups of 8
            int row = c >> 2, cg = c & 3;
            *reinterpret_cast<uint4*>(&As[row][cg * 8]) =
                *reinterpret_cast<const uint4*>(&xb[(size_t)(m0 + row) * CC + k0 + cg * 8]);
            *reinterpret_cast<uint4*>(&Bs[row][cg * 8]) =
                *reinterpret_cast<const uint4*>(&W[(size_t)(n0 + row) * CC + k0 + cg * 8]);
        }
        __syncthreads();
        bf16x8 a[4], b[4];
#pragma unroll
        for (int mi = 0; mi < 4; mi++)
            a[mi] = *reinterpret_cast<const bf16x8*>(&As[wr * 64 + mi * 16 + fr][fg * 8]);
#pragma unroll
        for (int ni = 0; ni < 4; ni++)
            b[ni] = *reinterpret_cast<const bf16x8*>(&Bs[wc * 64 + ni * 16 + fr][fg * 8]);
#pragma unroll
        for (int mi = 0; mi < 4; mi++)
#pragma unroll
            for (int ni = 0; ni < 4; ni++)
                acc[mi][ni] = __builtin_amdgcn_mfma_f32_16x16x32_bf16(
                    a[mi], b[ni], acc[mi][ni], 0, 0, 0);
    }

#pragma unroll
    for (int mi = 0; mi < 4; mi++)
#pragma unroll
        for (int ni = 0; ni < 4; ni++) {
            int n = n0 + wc * 64 + ni * 16 + fr;
            int h = n >> 6, d = n & 63;
            float bv_ = bias[n];
#pragma unroll
            for (int r = 0; r < 4; r++) {
                int m = m0 + wr * 64 + mi * 16 + fg * 4 + r;
                int b_ = m / TT, t = m % TT;
                size_t off = ((size_t)(b_ * NH + h) * TT + t) * (size_t)HD + d;
                out[off] = f2bf((acc[mi][ni][r] + bv_) * scale);
            }
        }
}

// ---------------------------------------------------------------------------
// Output projection GEMM: same structure, fp32 output [M, C] = d_out.
// ---------------------------------------------------------------------------
__global__ __launch_bounds__(256) void gemm_proj(
    const unsigned short* __restrict__ yb,
    const unsigned short* __restrict__ wp, const float* __restrict__ bp,
    float* __restrict__ out) {
    __shared__ unsigned short As[128][40];
    __shared__ unsigned short Bs[128][40];

    const int m0 = blockIdx.y * 128;
    const int n0 = blockIdx.x * 128;
    const int tid = threadIdx.x;
    const int lane = tid & 63;
    const int w = tid >> 6;
    const int wr = w >> 1, wc = w & 1;
    const int fr = lane & 15, fg = lane >> 4;

    f32x4 acc[4][4];
#pragma unroll
    for (int i = 0; i < 4; i++)
#pragma unroll
        for (int j = 0; j < 4; j++) acc[i][j] = (f32x4){0.f, 0.f, 0.f, 0.f};

    for (int k0 = 0; k0 < CC; k0 += 32) {
        __syncthreads();
        for (int c = tid; c < 512; c += 256) {
            int row = c >> 2, cg = c & 3;
            *reinterpret_cast<uint4*>(&As[row][cg * 8]) =
                *reinterpret_cast<const uint4*>(&yb[(size_t)(m0 + row) * CC + k0 + cg * 8]);
            *reinterpret_cast<uint4*>(&Bs[row][cg * 8]) =
                *reinterpret_cast<const uint4*>(&wp[(size_t)(n0 + row) * CC + k0 + cg * 8]);
        }
        __syncthreads();
        bf16x8 a[4], b[4];
#pragma unroll
        for (int mi = 0; mi < 4; mi++)
            a[mi] = *reinterpret_cast<const bf16x8*>(&As[wr * 64 + mi * 16 + fr][fg * 8]);
#pragma unroll
        for (int ni = 0; ni < 4; ni++)
            b[ni] = *reinterpret_cast<const bf16x8*>(&Bs[wc * 64 + ni * 16 + fr][fg * 8]);
#pragma unroll
        for (int mi = 0; mi < 4; mi++)
#pragma unroll
            for (int ni = 0; ni < 4; ni++)
                acc[mi][ni] = __builtin_amdgcn_mfma_f32_16x16x32_bf16(
                    a[mi], b[ni], acc[mi][ni], 0, 0, 0);
    }

#pragma unroll
    for (int mi = 0; mi < 4; mi++)
#pragma unroll
        for (int ni = 0; ni < 4; ni++) {
            int n = n0 + wc * 64 + ni * 16 + fr;
            float bv_ = bp[n];
#pragma unroll
            for (int r = 0; r < 4; r++) {
                int m = m0 + wr * 64 + mi * 16 + fg * 4 + r;
                out[(size_t)m * CC + n] = acc[mi][ni][r] + bv_;
            }
        }
}

// ---------------------------------------------------------------------------
// Flash attention with tiled-causal mask: valid iff (j%512) <= (i%512).
// Block: 64 Q-rows (4 waves x 16 rows), K-chunks of 32, online softmax.
// q pre-scaled by 1/sqrt(D). Writes y as bf16 [B,T,C].
// ---------------------------------------------------------------------------
__global__ __launch_bounds__(256) void attn(
    const unsigned short* __restrict__ q, const unsigned short* __restrict__ k,
    const unsigned short* __restrict__ v, unsigned short* __restrict__ y) {
    __shared__ unsigned short Ks[32][72];       // [key][d], pad -> 2-way max
    __shared__ unsigned short Vt[64][40];       // [d][key] transposed
    __shared__ unsigned short Ps[4][16][40];    // per-wave P relayout buffer

    const int bh = blockIdx.y;                  // b*NH + h
    const int q0 = blockIdx.x * 64;
    const int tid = threadIdx.x;
    const int w = tid >> 6;
    const int lane = tid & 63;
    const int fr = lane & 15, fg = lane >> 4;

    const size_t base = (size_t)bh * TT * HD;

    // Q fragments, resident whole kernel: rows q0+w*16+fr, d = s*32 + fg*8..+7
    bf16x8 aq[2];
#pragma unroll
    for (int s = 0; s < 2; s++)
        aq[s] = *reinterpret_cast<const bf16x8*>(
            &q[base + (size_t)(q0 + w * 16 + fr) * HD + s * 32 + fg * 8]);

    f32x4 acc_o[4];
#pragma unroll
    for (int i = 0; i < 4; i++) acc_o[i] = (f32x4){0.f, 0.f, 0.f, 0.f};
    float mrow[4] = {-1e30f, -1e30f, -1e30f, -1e30f};
    float lrow[4] = {0.f, 0.f, 0.f, 0.f};

    const int qb = q0 & 511;

    for (int k0 = 0; k0 < TT; k0 += 32) {
        const int kb = k0 & 511;
        if (kb > qb + 63) continue;            // chunk fully masked (uniform)
        __syncthreads();
        {   // stage K [32][64] and V^T [64][32]
            int kk = tid >> 3, dg = tid & 7;
            *reinterpret_cast<uint4*>(&Ks[kk][dg * 8]) =
                *reinterpret_cast<const uint4*>(&k[base + (size_t)(k0 + kk) * HD + dg * 8]);
            uint4 vv = *reinterpret_cast<const uint4*>(&v[base + (size_t)(k0 + kk) * HD + dg * 8]);
            unsigned short vs[8];
            *reinterpret_cast<uint4*>(vs) = vv;
#pragma unroll
            for (int j = 0; j < 8; j++) Vt[dg * 8 + j][kk] = vs[j];
        }
        __syncthreads();

        // S = Q K^T (16 q-rows x 32 keys per wave)
        f32x4 S[2];
#pragma unroll
        for (int nb = 0; nb < 2; nb++) {
            f32x4 sa = (f32x4){0.f, 0.f, 0.f, 0.f};
#pragma unroll
            for (int s = 0; s < 2; s++) {
                bf16x8 bk_ = *reinterpret_cast<const bf16x8*>(&Ks[nb * 16 + fr][s * 32 + fg * 8]);
                sa = __builtin_amdgcn_mfma_f32_16x16x32_bf16(aq[s], bk_, sa, 0, 0, 0);
            }
            S[nb] = sa;
        }

        if (kb + 31 > qb) {                    // partial chunk: elementwise mask
#pragma unroll
            for (int nb = 0; nb < 2; nb++)
#pragma unroll
                for (int r = 0; r < 4; r++) {
                    int row = w * 16 + fg * 4 + r;
                    int jj = nb * 16 + fr;
                    if (kb + jj > qb + row) S[nb][r] = -1e30f;
                }
        }

        // online softmax (rows live across 16 lanes sharing fg)
        float psc[4];
#pragma unroll
        for (int r = 0; r < 4; r++) {
            float mr = fmaxf(S[0][r], S[1][r]);
#pragma unroll
            for (int off = 1; off < 16; off <<= 1) mr = fmaxf(mr, __shfl_xor(mr, off));
            float mnew = fmaxf(mrow[r], mr);
            float p0 = __expf(S[0][r] - mnew);
            float p1 = __expf(S[1][r] - mnew);
            float sc = __expf(mrow[r] - mnew);
            S[0][r] = p0;
            S[1][r] = p1;
            float rs = p0 + p1;
#pragma unroll
            for (int off = 1; off < 16; off <<= 1) rs += __shfl_xor(rs, off);
            lrow[r] = lrow[r] * sc + rs;
            mrow[r] = mnew;
            psc[r] = sc;
        }
#pragma unroll
        for (int nd = 0; nd < 4; nd++)
#pragma unroll
            for (int r = 0; r < 4; r++) acc_o[nd][r] *= psc[r];

        // P (C-layout) -> LDS -> A-fragment layout (same wave, in-order DS)
#pragma unroll
        for (int nb = 0; nb < 2; nb++)
#pragma unroll
            for (int r = 0; r < 4; r++)
                Ps[w][fg * 4 + r][nb * 16 + fr] = f2bf(S[nb][r]);

        bf16x8 ap = *reinterpret_cast<const bf16x8*>(&Ps[w][fr][fg * 8]);
#pragma unroll
        for (int nd = 0; nd < 4; nd++) {
            bf16x8 bv_ = *reinterpret_cast<const bf16x8*>(&Vt[nd * 16 + fr][fg * 8]);
            acc_o[nd] = __builtin_amdgcn_mfma_f32_16x16x32_bf16(ap, bv_, acc_o[nd], 0, 0, 0);
        }
    }

    // finalize: y[b][t][h*64+d] bf16
    const int b_ = bh / NH, h = bh % NH;
#pragma unroll
    for (int r = 0; r < 4; r++) {
        float inv = 1.f / lrow[r];
        int t = q0 + w * 16 + fg * 4 + r;
        size_t off = ((size_t)b_ * TT + t) * CC + h * HD;
#pragma unroll
        for (int nd = 0; nd < 4; nd++)
            y[off + nd * 16 + fr] = f2bf(acc_o[nd][r] * inv);
    }
}

extern "C" void kernel_launch(void* const* d_in, const int* in_sizes, int n_in,
                              void* d_out, int out_size, void* d_ws, size_t ws_size,
                              hipStream_t stream) {
    const float* x  = (const float*)d_in[0];
    const float* Wq = (const float*)d_in[1];
    const float* bq = (const float*)d_in[2];
    const float* Wk = (const float*)d_in[3];
    const float* bk = (const float*)d_in[4];
    const float* Wv = (const float*)d_in[5];
    const float* bv = (const float*)d_in[6];
    const float* Wp = (const float*)d_in[7];
    const float* bp = (const float*)d_in[8];
    float* out = (float*)d_out;

    unsigned short* ws  = (unsigned short*)d_ws;
    unsigned short* xb  = ws;                              // MM*CC
    unsigned short* wqb = xb  + (size_t)MM * CC;           // CC*CC each
    unsigned short* wkb = wqb + (size_t)CC * CC;
    unsigned short* wvb = wkb + (size_t)CC * CC;
    unsigned short* wpb = wvb + (size_t)CC * CC;
    unsigned short* qb_ = wpb + (size_t)CC * CC;           // MM*CC each (=B*H*T*D)
    unsigned short* kb_ = qb_ + (size_t)MM * CC;
    unsigned short* vb_ = kb_ + (size_t)MM * CC;
    unsigned short* yb  = vb_ + (size_t)MM * CC;

    const int n4x = MM * CC / 4, n4w = CC * CC / 4;
    convert_k<<<(n4x + 255) / 256, 256, 0, stream>>>(x, xb, n4x);
    convert_k<<<(n4w + 255) / 256, 256, 0, stream>>>(Wq, wqb, n4w);
    convert_k<<<(n4w + 255) / 256, 256, 0, stream>>>(Wk, wkb, n4w);
    convert_k<<<(n4w + 255) / 256, 256, 0, stream>>>(Wv, wvb, n4w);
    convert_k<<<(n4w + 255) / 256, 256, 0, stream>>>(Wp, wpb, n4w);

    gemm_qkv<<<dim3(CC / 128, MM / 128, 3), 256, 0, stream>>>(
        xb, wqb, bq, wkb, bk, wvb, bv, qb_, kb_, vb_);
    attn<<<dim3(TT / 64, BB * NH), 256, 0, stream>>>(qb_, kb_, vb_, yb);
    gemm_proj<<<dim3(CC / 128, MM / 128), 256, 0, stream>>>(yb, wpb, bp, out);
}